// Round 2
// baseline (1261.047 us; speedup 1.0000x reference)
//
#include <hip/hip_runtime.h>
#include <hip/hip_bf16.h>

#define N_NODES 2048
#define L_SEQ   100
#define ROWS    (N_NODES * L_SEQ)   // 204800
#define HEADS   4
#define GHID    64

// ---------------- workspace layout (float offsets) ----------------
constexpr size_t OFF_WCOMB = 0;                          // 16*128
constexpr size_t OFF_BCOMB = OFF_WCOMB + 2048;           // 128
constexpr size_t OFF_AEXP  = OFF_BCOMB + 128;            // 16
constexpr size_t OFF_BM    = OFF_AEXP + 16 + 12;         // pad to 16B-multiple: 2192+12=2204? keep explicit below
// NOTE: need (OFF_BM*4) % 16 == 0 for float4 loads. 2192 % 4 == 0 -> ok without pad.
constexpr size_t OFF_BM_   = 2192;                       // ROWS*16
constexpr size_t OFF_CM_   = OFF_BM_ + (size_t)ROWS * 16;
constexpr size_t OFF_XT1   = OFF_CM_ + (size_t)ROWS * 16;            // 4*2048*64
constexpr size_t OFF_ES1   = OFF_XT1 + (size_t)HEADS * N_NODES * GHID;
constexpr size_t OFF_ED1   = OFF_ES1 + HEADS * N_NODES;
constexpr size_t OFF_H1    = OFF_ED1 + HEADS * N_NODES;  // 2048*256
constexpr size_t OFF_XT2   = OFF_H1 + (size_t)N_NODES * 256;
constexpr size_t OFF_ES2   = OFF_XT2 + (size_t)N_NODES * 64;
constexpr size_t OFF_ED2   = OFF_ES2 + N_NODES;

// ---------------- K0: Wcomb = Wo[:16]@Wfc, bcomb = bo@Wfc+bfc, Aexp ----------------
__global__ void k0_comb(const float* __restrict__ Wo, const float* __restrict__ bo,
                        const float* __restrict__ Wfc, const float* __restrict__ bfc,
                        const float* __restrict__ A_log, float* __restrict__ ws) {
    const int f2 = threadIdx.x;  // 128
    float acc = bfc[f2];
    for (int f = 0; f < 128; f++) acc += bo[f] * Wfc[f * 128 + f2];
    ws[OFF_BCOMB + f2] = acc;
    for (int s = 0; s < 16; s++) {
        float a = 0.f;
        for (int f = 0; f < 128; f++) a += Wo[s * 128 + f] * Wfc[f * 128 + f2];
        ws[OFF_WCOMB + s * 128 + f2] = a;
    }
    if (f2 < 16) ws[OFF_AEXP + f2] = expf(0.01f * expf(A_log[f2]));
}

// ---------------- K1: x=temporal+pos; gated=(x@Wi+bi)*sigmoid(x@Wg+bg);
//                  B=gated@Wb+bb ; C=x@Wc+bc  (16 rows per block) ----------------
__global__ __launch_bounds__(256) void k1_gate_bc(
    const float* __restrict__ temporal, const float* __restrict__ pos,
    const float* __restrict__ Wi, const float* __restrict__ bi,
    const float* __restrict__ Wg, const float* __restrict__ bg,
    const float* __restrict__ Wb, const float* __restrict__ bb,
    const float* __restrict__ Wc, const float* __restrict__ bc,
    float* __restrict__ Bm, float* __restrict__ Cm) {
    __shared__ float xs[16][129];
    __shared__ float gs[16][257];
    const int tid = threadIdx.x;
    const int r0  = blockIdx.x * 16;

    // phase 1: stage x = temporal + pos
    for (int i = tid; i < 16 * 128; i += 256) {
        int row = i >> 7, d = i & 127;
        int r = r0 + row;
        int l = r % L_SEQ;
        xs[row][d] = temporal[(size_t)r * 128 + d] + pos[l * 128 + d];
    }
    __syncthreads();

    // phase 2: gated linear, 2 rows x 8 cols per thread
    const int cg = tid & 31, rp = tid >> 5;
    const int row0 = rp * 2, c0 = cg * 8;
    float accI[2][8] = {}, accG[2][8] = {};
    for (int k = 0; k < 128; k++) {
        float a0 = xs[row0][k], a1 = xs[row0 + 1][k];
        float wiv[8], wgv[8];
        *(float4*)&wiv[0] = *(const float4*)(Wi + (size_t)k * 256 + c0);
        *(float4*)&wiv[4] = *(const float4*)(Wi + (size_t)k * 256 + c0 + 4);
        *(float4*)&wgv[0] = *(const float4*)(Wg + (size_t)k * 256 + c0);
        *(float4*)&wgv[4] = *(const float4*)(Wg + (size_t)k * 256 + c0 + 4);
#pragma unroll
        for (int c = 0; c < 8; c++) {
            accI[0][c] += a0 * wiv[c]; accI[1][c] += a1 * wiv[c];
            accG[0][c] += a0 * wgv[c]; accG[1][c] += a1 * wgv[c];
        }
    }
#pragma unroll
    for (int rr = 0; rr < 2; rr++)
#pragma unroll
        for (int c = 0; c < 8; c++) {
            float li = accI[rr][c] + bi[c0 + c];
            float lg = accG[rr][c] + bg[c0 + c];
            gs[row0 + rr][c0 + c] = li * (1.f / (1.f + expf(-lg)));
        }
    __syncthreads();

    // phase 3: B = gated @ Wb + bb ; phase 4: C = x @ Wc + bc
    {
        const int s = tid & 15, row = tid >> 4;
        float acc = bb[s];
        for (int d = 0; d < 256; d++) acc += gs[row][d] * Wb[d * 16 + s];
        Bm[(size_t)(r0 + row) * 16 + s] = acc;

        float accc = bc[s];
        for (int d = 0; d < 128; d++) accc += xs[row][d] * Wc[d * 16 + s];
        Cm[(size_t)(r0 + row) * 16 + s] = accc;
    }
}

// ---------------- K2: scan over L + fused y@Wcomb+bcomb epilogue ----------------
__global__ __launch_bounds__(128) void k2_scan(const float* __restrict__ ws,
                                               float* __restrict__ out) {
    const int n = blockIdx.x, f = threadIdx.x;
    const float* Bm = ws + OFF_BM_;
    const float* Cm = ws + OFF_CM_;
    float w[16], A[16], h[16];
#pragma unroll
    for (int s = 0; s < 16; s++) {
        w[s] = ws[OFF_WCOMB + s * 128 + f];
        A[s] = ws[OFF_AEXP + s];
        h[s] = 0.f;
    }
    const float bcb = ws[OFF_BCOMB + f];
    for (int l = 0; l < L_SEQ; l++) {
        const size_t base = ((size_t)n * L_SEQ + l) * 16;
        float bv[16], cv[16];
#pragma unroll
        for (int q = 0; q < 4; q++) {
            ((float4*)bv)[q] = ((const float4*)(Bm + base))[q];
            ((float4*)cv)[q] = ((const float4*)(Cm + base))[q];
        }
        float acc = bcb;
#pragma unroll
        for (int s = 0; s < 16; s++) {
            h[s] = A[s] * h[s] + bv[s];
            acc += h[s] * cv[s] * w[s];
        }
        out[((size_t)n * L_SEQ + l) * 128 + f] = acc;
    }
}

// ---------------- K4: xt1 = x@W1 per head, + es1/ed1 reductions ----------------
__global__ __launch_bounds__(64) void k4_xt1(const float* __restrict__ gx,
                                             const float* __restrict__ W1,
                                             const float* __restrict__ a1,
                                             float* __restrict__ ws) {
    const int b = blockIdx.x;     // 0..8191
    const int h = b >> 11;
    const int n = b & 2047;
    const int o = threadIdx.x;    // 64
    float acc = 0.f;
    for (int f = 0; f < 128; f++)
        acc += gx[n * 128 + f] * W1[(h * 128 + f) * 64 + o];
    ws[OFF_XT1 + ((size_t)h * 2048 + n) * 64 + o] = acc;
    float es = acc * a1[h * 128 + o];
    float ed = acc * a1[h * 128 + 64 + o];
#pragma unroll
    for (int off = 32; off > 0; off >>= 1) {
        es += __shfl_down(es, off);
        ed += __shfl_down(ed, off);
    }
    if (o == 0) { ws[OFF_ES1 + h * 2048 + n] = es; ws[OFF_ED1 + h * 2048 + n] = ed; }
}

// ---------------- K5: layer-1 attention (sparse) + relu -> h1 ----------------
__global__ __launch_bounds__(256) void k5_att1(const float* __restrict__ adj,
                                               const float* __restrict__ ws,
                                               float* __restrict__ h1out) {
    __shared__ int list[2048];
    __shared__ int cnt;
    const int n = blockIdx.x, tid = threadIdx.x;
    if (tid == 0) cnt = 0;
    __syncthreads();
    for (int j = tid; j < 2048; j += 256)
        if (adj[(size_t)n * 2048 + j] > 0.f) list[atomicAdd(&cnt, 1)] = j;
    __syncthreads();
    const int h = tid >> 6, o = tid & 63;
    const float  es = ws[OFF_ES1 + h * 2048 + n];
    const float* ed = ws + OFF_ED1 + h * 2048;
    const float* xt = ws + OFF_XT1 + (size_t)h * 2048 * 64;
    float num = 0.f, den = 0.f;
    const int m = cnt;
    for (int ii = 0; ii < m; ii++) {
        int j = list[ii];
        float e = es + ed[j];
        e = (e > 0.f) ? e : 0.2f * e;
        float wgt = expf(e);
        den += wgt;
        num += wgt * xt[(size_t)j * 64 + o];
    }
    float v = num / den;
    h1out[(size_t)n * 256 + h * 64 + o] = v > 0.f ? v : 0.f;
}

// ---------------- K6: xt2 = h1@W2 + es2/ed2 ----------------
__global__ __launch_bounds__(64) void k6_xt2(const float* __restrict__ W2,
                                             const float* __restrict__ a2,
                                             float* __restrict__ ws) {
    const int n = blockIdx.x, o = threadIdx.x;
    const float* h1 = ws + OFF_H1 + (size_t)n * 256;
    float acc = 0.f;
    for (int f = 0; f < 256; f++) acc += h1[f] * W2[f * 64 + o];
    ws[OFF_XT2 + (size_t)n * 64 + o] = acc;
    float es = acc * a2[o];
    float ed = acc * a2[64 + o];
#pragma unroll
    for (int off = 32; off > 0; off >>= 1) {
        es += __shfl_down(es, off);
        ed += __shfl_down(ed, off);
    }
    if (o == 0) { ws[OFF_ES2 + n] = es; ws[OFF_ED2 + n] = ed; }
}

// ---------------- K7: layer-2 attention (sparse) -> gat out ----------------
__global__ __launch_bounds__(64) void k7_att2(const float* __restrict__ adj,
                                              const float* __restrict__ ws,
                                              float* __restrict__ gout) {
    __shared__ int list[2048];
    __shared__ int cnt;
    const int n = blockIdx.x, o = threadIdx.x;
    if (o == 0) cnt = 0;
    __syncthreads();
    for (int j = o; j < 2048; j += 64)
        if (adj[(size_t)n * 2048 + j] > 0.f) list[atomicAdd(&cnt, 1)] = j;
    __syncthreads();
    const float es = ws[OFF_ES2 + n];
    float num = 0.f, den = 0.f;
    const int m = cnt;
    for (int ii = 0; ii < m; ii++) {
        int j = list[ii];
        float e = es + ws[OFF_ED2 + j];
        e = (e > 0.f) ? e : 0.2f * e;
        float wgt = expf(e);
        den += wgt;
        num += wgt * ws[OFF_XT2 + (size_t)j * 64 + o];
    }
    gout[(size_t)n * 64 + o] = num / den;
}

extern "C" void kernel_launch(void* const* d_in, const int* in_sizes, int n_in,
                              void* d_out, int out_size, void* d_ws, size_t ws_size,
                              hipStream_t stream) {
    const float* temporal = (const float*)d_in[0];
    const float* graph_x  = (const float*)d_in[1];
    const float* adj      = (const float*)d_in[2];
    const float* pos      = (const float*)d_in[3];
    const float* Wi  = (const float*)d_in[4];
    const float* bi  = (const float*)d_in[5];
    const float* Wg  = (const float*)d_in[6];
    const float* bg  = (const float*)d_in[7];
    const float* A_log = (const float*)d_in[8];
    const float* Wb  = (const float*)d_in[9];
    const float* bb  = (const float*)d_in[10];
    const float* Wc  = (const float*)d_in[11];
    const float* bc  = (const float*)d_in[12];
    const float* Wo  = (const float*)d_in[13];
    const float* bo  = (const float*)d_in[14];
    const float* Wfc = (const float*)d_in[15];
    const float* bfc = (const float*)d_in[16];
    const float* W1  = (const float*)d_in[17];
    const float* a1  = (const float*)d_in[18];
    const float* W2  = (const float*)d_in[19];
    const float* a2  = (const float*)d_in[20];

    float* ws = (float*)d_ws;
    float* out_mamba = (float*)d_out;
    float* out_gat   = out_mamba + (size_t)ROWS * 128;

    k0_comb<<<1, 128, 0, stream>>>(Wo, bo, Wfc, bfc, A_log, ws);
    k1_gate_bc<<<ROWS / 16, 256, 0, stream>>>(temporal, pos, Wi, bi, Wg, bg,
                                              Wb, bb, Wc, bc,
                                              ws + OFF_BM_, ws + OFF_CM_);
    k2_scan<<<N_NODES, 128, 0, stream>>>(ws, out_mamba);
    k4_xt1<<<HEADS * N_NODES, 64, 0, stream>>>(graph_x, W1, a1, ws);
    k5_att1<<<N_NODES, 256, 0, stream>>>(adj, ws, ws + OFF_H1);
    k6_xt2<<<N_NODES, 64, 0, stream>>>(W2, a2, ws);
    k7_att2<<<N_NODES, 64, 0, stream>>>(adj, ws, out_gat);
}

// Round 3
// 496.684 us; speedup vs baseline: 2.5389x; 2.5389x over previous
//
#include <hip/hip_runtime.h>
#include <hip/hip_bf16.h>

#define N_NODES 2048
#define L_SEQ   100
#define ROWS    (N_NODES * L_SEQ)   // 204800
#define HEADS   4
#define GHID    64

typedef __attribute__((ext_vector_type(8))) short bf16x8;
typedef __attribute__((ext_vector_type(4))) float floatx4;

__device__ __forceinline__ short f2bf(float f) {
    union { float f; unsigned u; } v; v.f = f;
    unsigned r = v.u + 0x7fffu + ((v.u >> 16) & 1u);   // RNE
    return (short)(r >> 16);
}

// ---------------- workspace layout (float offsets) ----------------
constexpr size_t OFF_WCOMB = 0;                           // 16*128
constexpr size_t OFF_BCOMB = 2048;                        // 128
constexpr size_t OFF_AEXP  = 2176;                        // 16
constexpr size_t OFF_WIGS  = 2192;                        // 65536 bf16 (32768 f)
constexpr size_t OFF_WBS   = 34960;                       // 4096 bf16 (2048 f)
constexpr size_t OFF_WCS   = 37008;                       // 2048 bf16 (1024 f)
constexpr size_t OFF_BM    = 38032;                       // ROWS*16
constexpr size_t OFF_CM    = OFF_BM + (size_t)ROWS * 16;  // ROWS*16 (end 26.4 MB)
// GAT scratch aliases the Bm region (dead after k2_scan):
constexpr size_t OFF_XT1   = OFF_BM;                      // 4*2048*64
constexpr size_t OFF_ES1   = OFF_XT1 + (size_t)HEADS * N_NODES * GHID;
constexpr size_t OFF_ED1   = OFF_ES1 + HEADS * N_NODES;
constexpr size_t OFF_H1    = OFF_ED1 + HEADS * N_NODES;   // 2048*256
constexpr size_t OFF_XT2   = OFF_H1 + (size_t)N_NODES * 256;
constexpr size_t OFF_ES2   = OFF_XT2 + (size_t)N_NODES * 64;
constexpr size_t OFF_ED2   = OFF_ES2 + N_NODES;

// ---------------- K0a: Wcomb = Wo[:16]@Wfc, bcomb = bo@Wfc+bfc, Aexp ----------------
__global__ void k0_comb(const float* __restrict__ Wo, const float* __restrict__ bo,
                        const float* __restrict__ Wfc, const float* __restrict__ bfc,
                        const float* __restrict__ A_log, float* __restrict__ ws) {
    const int f2 = threadIdx.x;  // 128
    float acc = bfc[f2];
    for (int f = 0; f < 128; f++) acc += bo[f] * Wfc[f * 128 + f2];
    ws[OFF_BCOMB + f2] = acc;
    for (int s = 0; s < 16; s++) {
        float a = 0.f;
        for (int f = 0; f < 128; f++) a += Wo[s * 128 + f] * Wfc[f * 128 + f2];
        ws[OFF_WCOMB + s * 128 + f2] = a;
    }
    if (f2 < 16) ws[OFF_AEXP + f2] = expf(0.01f * expf(A_log[f2]));
}

// ---------------- K0b: swizzle Wi|Wg, Wb, Wc into bf16 B-fragment order ----------------
// B-frag layout (16x16x32): n = lane&15, k = (lane>>4)*8 + j, j=0..7
__global__ void k0_prep(const float* __restrict__ Wi, const float* __restrict__ Wg,
                        const float* __restrict__ Wb, const float* __restrict__ Wc,
                        float* __restrict__ ws) {
    int i = blockIdx.x * 256 + threadIdx.x;
    short* wigs = (short*)(ws + OFF_WIGS);
    short* wbs  = (short*)(ws + OFF_WBS);
    short* wcs  = (short*)(ws + OFF_WCS);
    if (i < 65536) {
        // nt = w*8 + t; t<4 -> I-tile cols 64w+16t.. ; t>=4 -> G-tile (same cols of Wg)
        int j = i & 7, lane = (i >> 3) & 63, ks = (i >> 9) & 3, nt = i >> 11;
        int w = nt >> 3, t = nt & 7;
        int col = w * 64 + (t & 3) * 16 + (lane & 15);
        int k   = ks * 32 + (lane >> 4) * 8 + j;
        float v = (t < 4) ? Wi[k * 256 + col] : Wg[k * 256 + col];
        wigs[i] = f2bf(v);
    } else if (i < 65536 + 4096) {
        int ii = i - 65536;
        int j = ii & 7, lane = (ii >> 3) & 63, ks = ii >> 9;       // ks 0..7
        int k = ks * 32 + (lane >> 4) * 8 + j, n = lane & 15;
        wbs[ii] = f2bf(Wb[k * 16 + n]);
    } else if (i < 65536 + 4096 + 2048) {
        int ii = i - 65536 - 4096;
        int j = ii & 7, lane = (ii >> 3) & 63, ks = ii >> 9;       // ks 0..3
        int k = ks * 32 + (lane >> 4) * 8 + j, n = lane & 15;
        wcs[ii] = f2bf(Wc[k * 16 + n]);
    }
}

// ---------------- K1: MFMA gated GEMM + gating + B/C GEMMs ----------------
// block = 64 rows, 4 waves; wave w owns I-cols & G-cols [64w, 64w+64)
__global__ __launch_bounds__(256) void k1_mfma(
    const float* __restrict__ temporal, const float* __restrict__ pos,
    const float* __restrict__ bi, const float* __restrict__ bg,
    const float* __restrict__ bb, const float* __restrict__ bc,
    const float* __restrict__ ws, float* __restrict__ Bm, float* __restrict__ Cm) {
    __shared__ short xbf[64][136];   // +8 pad: 2-way bank alias only (free)
    __shared__ short gbf[64][264];   // +8 pad
    const int tid = threadIdx.x, wave = tid >> 6, lane = tid & 63;
    const int m = lane & 15, quad = lane >> 4;
    const int r0 = blockIdx.x * 64;

    // stage x = temporal + pos -> bf16 LDS
#pragma unroll
    for (int i = 0; i < 8; i++) {
        int f4  = i * 256 + tid;          // 2048 float4s = 64 rows x 32
        int row = f4 >> 5;
        int c4  = (f4 & 31) * 4;
        int r = r0 + row, l = r % L_SEQ;
        float4 tv = *(const float4*)(temporal + (size_t)r * 128 + c4);
        float4 pv = *(const float4*)(pos + l * 128 + c4);
        short4 sv;
        sv.x = f2bf(tv.x + pv.x); sv.y = f2bf(tv.y + pv.y);
        sv.z = f2bf(tv.z + pv.z); sv.w = f2bf(tv.w + pv.w);
        *(short4*)&xbf[row][c4] = sv;
    }
    __syncthreads();

    // main gated GEMM: per wave 4 M-tiles x (4 I-tiles + 4 G-tiles), K=128
    const short* Wigs = (const short*)(ws + OFF_WIGS);
    floatx4 acc[4][8] = {};
#pragma unroll
    for (int ks = 0; ks < 4; ks++) {
        bf16x8 bfr[8];
#pragma unroll
        for (int nt = 0; nt < 8; nt++)
            bfr[nt] = *(const bf16x8*)(Wigs + (size_t)(((wave * 8 + nt) * 4 + ks) * 64 + lane) * 8);
        bf16x8 afr[4];
#pragma unroll
        for (int mt = 0; mt < 4; mt++)
            afr[mt] = *(const bf16x8*)&xbf[mt * 16 + m][ks * 32 + quad * 8];
#pragma unroll
        for (int mt = 0; mt < 4; mt++)
#pragma unroll
            for (int nt = 0; nt < 8; nt++)
                acc[mt][nt] = __builtin_amdgcn_mfma_f32_16x16x32_bf16(
                    afr[mt], bfr[nt], acc[mt][nt], 0, 0, 0);
    }

    // gating: gated = (I+bi)*sigmoid(G+bg); C/D layout col=lane&15, row=quad*4+r
#pragma unroll
    for (int tp = 0; tp < 4; tp++) {
        int col = wave * 64 + tp * 16 + m;
        float biv = bi[col], bgv = bg[col];
#pragma unroll
        for (int mt = 0; mt < 4; mt++) {
#pragma unroll
            for (int r = 0; r < 4; r++) {
                float li = acc[mt][tp][r] + biv;
                float lg = acc[mt][tp + 4][r] + bgv;
                float g = li / (1.f + expf(-lg));
                gbf[mt * 16 + quad * 4 + r][col] = f2bf(g);
            }
        }
    }
    __syncthreads();

    // B = gated@Wb + bb (K=256) ; C = x@Wc + bc (K=128); wave w -> M-tile w
    const short* Wbs = (const short*)(ws + OFF_WBS);
    const short* Wcs = (const short*)(ws + OFF_WCS);
    floatx4 accB = {}, accC = {};
#pragma unroll
    for (int ks = 0; ks < 8; ks++) {
        bf16x8 a = *(const bf16x8*)&gbf[wave * 16 + m][ks * 32 + quad * 8];
        bf16x8 b = *(const bf16x8*)(Wbs + (size_t)(ks * 64 + lane) * 8);
        accB = __builtin_amdgcn_mfma_f32_16x16x32_bf16(a, b, accB, 0, 0, 0);
    }
#pragma unroll
    for (int ks = 0; ks < 4; ks++) {
        bf16x8 a = *(const bf16x8*)&xbf[wave * 16 + m][ks * 32 + quad * 8];
        bf16x8 b = *(const bf16x8*)(Wcs + (size_t)(ks * 64 + lane) * 8);
        accC = __builtin_amdgcn_mfma_f32_16x16x32_bf16(a, b, accC, 0, 0, 0);
    }
    float bbv = bb[m], bcv = bc[m];
#pragma unroll
    for (int r = 0; r < 4; r++) {
        int row = r0 + wave * 16 + quad * 4 + r;
        Bm[(size_t)row * 16 + m] = accB[r] + bbv;
        Cm[(size_t)row * 16 + m] = accC[r] + bcv;
    }
}

// ---------------- K2: scan over L + fused y@Wcomb+bcomb epilogue ----------------
__global__ __launch_bounds__(128) void k2_scan(const float* __restrict__ ws,
                                               float* __restrict__ out) {
    const int n = blockIdx.x, f = threadIdx.x;
    const float* Bm = ws + OFF_BM;
    const float* Cm = ws + OFF_CM;
    float w[16], A[16], h[16];
#pragma unroll
    for (int s = 0; s < 16; s++) {
        w[s] = ws[OFF_WCOMB + s * 128 + f];
        A[s] = ws[OFF_AEXP + s];
        h[s] = 0.f;
    }
    const float bcb = ws[OFF_BCOMB + f];
    for (int l = 0; l < L_SEQ; l++) {
        const size_t base = ((size_t)n * L_SEQ + l) * 16;
        float bv[16], cv[16];
#pragma unroll
        for (int q = 0; q < 4; q++) {
            ((float4*)bv)[q] = ((const float4*)(Bm + base))[q];
            ((float4*)cv)[q] = ((const float4*)(Cm + base))[q];
        }
        float acc = bcb;
#pragma unroll
        for (int s = 0; s < 16; s++) {
            h[s] = A[s] * h[s] + bv[s];
            acc += h[s] * cv[s] * w[s];
        }
        out[((size_t)n * L_SEQ + l) * 128 + f] = acc;
    }
}

// ---------------- K4: xt1 = x@W1 per head, + es1/ed1 reductions ----------------
__global__ __launch_bounds__(64) void k4_xt1(const float* __restrict__ gx,
                                             const float* __restrict__ W1,
                                             const float* __restrict__ a1,
                                             float* __restrict__ ws) {
    const int b = blockIdx.x;     // 0..8191
    const int h = b >> 11;
    const int n = b & 2047;
    const int o = threadIdx.x;    // 64
    float acc = 0.f;
    for (int f = 0; f < 128; f++)
        acc += gx[n * 128 + f] * W1[(h * 128 + f) * 64 + o];
    ws[OFF_XT1 + ((size_t)h * 2048 + n) * 64 + o] = acc;
    float es = acc * a1[h * 128 + o];
    float ed = acc * a1[h * 128 + 64 + o];
#pragma unroll
    for (int off = 32; off > 0; off >>= 1) {
        es += __shfl_down(es, off);
        ed += __shfl_down(ed, off);
    }
    if (o == 0) { ws[OFF_ES1 + h * 2048 + n] = es; ws[OFF_ED1 + h * 2048 + n] = ed; }
}

// ---------------- K5: layer-1 attention (sparse) + relu -> h1 ----------------
__global__ __launch_bounds__(256) void k5_att1(const float* __restrict__ adj,
                                               const float* __restrict__ ws,
                                               float* __restrict__ h1out) {
    __shared__ int list[2048];
    __shared__ int cnt;
    const int n = blockIdx.x, tid = threadIdx.x;
    if (tid == 0) cnt = 0;
    __syncthreads();
    for (int j = tid; j < 2048; j += 256)
        if (adj[(size_t)n * 2048 + j] > 0.f) list[atomicAdd(&cnt, 1)] = j;
    __syncthreads();
    const int h = tid >> 6, o = tid & 63;
    const float  es = ws[OFF_ES1 + h * 2048 + n];
    const float* ed = ws + OFF_ED1 + h * 2048;
    const float* xt = ws + OFF_XT1 + (size_t)h * 2048 * 64;
    float num = 0.f, den = 0.f;
    const int mm = cnt;
    for (int ii = 0; ii < mm; ii++) {
        int j = list[ii];
        float e = es + ed[j];
        e = (e > 0.f) ? e : 0.2f * e;
        float wgt = expf(e);
        den += wgt;
        num += wgt * xt[(size_t)j * 64 + o];
    }
    float v = num / den;
    h1out[(size_t)n * 256 + h * 64 + o] = v > 0.f ? v : 0.f;
}

// ---------------- K6: xt2 = h1@W2 + es2/ed2 ----------------
__global__ __launch_bounds__(64) void k6_xt2(const float* __restrict__ W2,
                                             const float* __restrict__ a2,
                                             float* __restrict__ ws) {
    const int n = blockIdx.x, o = threadIdx.x;
    const float* h1 = ws + OFF_H1 + (size_t)n * 256;
    float acc = 0.f;
    for (int f = 0; f < 256; f++) acc += h1[f] * W2[f * 64 + o];
    ws[OFF_XT2 + (size_t)n * 64 + o] = acc;
    float es = acc * a2[o];
    float ed = acc * a2[64 + o];
#pragma unroll
    for (int off = 32; off > 0; off >>= 1) {
        es += __shfl_down(es, off);
        ed += __shfl_down(ed, off);
    }
    if (o == 0) { ws[OFF_ES2 + n] = es; ws[OFF_ED2 + n] = ed; }
}

// ---------------- K7: layer-2 attention (sparse) -> gat out ----------------
__global__ __launch_bounds__(64) void k7_att2(const float* __restrict__ adj,
                                              const float* __restrict__ ws,
                                              float* __restrict__ gout) {
    __shared__ int list[2048];
    __shared__ int cnt;
    const int n = blockIdx.x, o = threadIdx.x;
    if (o == 0) cnt = 0;
    __syncthreads();
    for (int j = o; j < 2048; j += 64)
        if (adj[(size_t)n * 2048 + j] > 0.f) list[atomicAdd(&cnt, 1)] = j;
    __syncthreads();
    const float es = ws[OFF_ES2 + n];
    float num = 0.f, den = 0.f;
    const int mm = cnt;
    for (int ii = 0; ii < mm; ii++) {
        int j = list[ii];
        float e = es + ws[OFF_ED2 + j];
        e = (e > 0.f) ? e : 0.2f * e;
        float wgt = expf(e);
        den += wgt;
        num += wgt * ws[OFF_XT2 + (size_t)j * 64 + o];
    }
    gout[(size_t)n * 64 + o] = num / den;
}

extern "C" void kernel_launch(void* const* d_in, const int* in_sizes, int n_in,
                              void* d_out, int out_size, void* d_ws, size_t ws_size,
                              hipStream_t stream) {
    const float* temporal = (const float*)d_in[0];
    const float* graph_x  = (const float*)d_in[1];
    const float* adj      = (const float*)d_in[2];
    const float* pos      = (const float*)d_in[3];
    const float* Wi  = (const float*)d_in[4];
    const float* bi  = (const float*)d_in[5];
    const float* Wg  = (const float*)d_in[6];
    const float* bg  = (const float*)d_in[7];
    const float* A_log = (const float*)d_in[8];
    const float* Wb  = (const float*)d_in[9];
    const float* bb  = (const float*)d_in[10];
    const float* Wc  = (const float*)d_in[11];
    const float* bc  = (const float*)d_in[12];
    const float* Wo  = (const float*)d_in[13];
    const float* bo  = (const float*)d_in[14];
    const float* Wfc = (const float*)d_in[15];
    const float* bfc = (const float*)d_in[16];
    const float* W1  = (const float*)d_in[17];
    const float* a1  = (const float*)d_in[18];
    const float* W2  = (const float*)d_in[19];
    const float* a2  = (const float*)d_in[20];

    float* ws = (float*)d_ws;
    float* out_mamba = (float*)d_out;
    float* out_gat   = out_mamba + (size_t)ROWS * 128;

    k0_comb<<<1, 128, 0, stream>>>(Wo, bo, Wfc, bfc, A_log, ws);
    k0_prep<<<280, 256, 0, stream>>>(Wi, Wg, Wb, Wc, ws);
    k1_mfma<<<ROWS / 64, 256, 0, stream>>>(temporal, pos, bi, bg, bb, bc, ws,
                                           ws + OFF_BM, ws + OFF_CM);
    k2_scan<<<N_NODES, 128, 0, stream>>>(ws, out_mamba);
    k4_xt1<<<HEADS * N_NODES, 64, 0, stream>>>(graph_x, W1, a1, ws);
    k5_att1<<<N_NODES, 256, 0, stream>>>(adj, ws, ws + OFF_H1);
    k6_xt2<<<N_NODES, 64, 0, stream>>>(W2, a2, ws);
    k7_att2<<<N_NODES, 64, 0, stream>>>(adj, ws, out_gat);
}

// Round 4
// 378.377 us; speedup vs baseline: 3.3328x; 1.3127x over previous
//
#include <hip/hip_runtime.h>
#include <hip/hip_bf16.h>

#define N_NODES 2048
#define L_SEQ   100
#define ROWS    (N_NODES * L_SEQ)   // 204800
#define HEADS   4
#define GHID    64

typedef __attribute__((ext_vector_type(8))) short bf16x8;
typedef __attribute__((ext_vector_type(4))) float floatx4;

// round-half-up bf16 cvt: 2 VALU (add, shift). <=1 ulp diff vs RNE (ties only).
__device__ __forceinline__ short f2bf(float f) {
    union { float f; unsigned u; } v; v.f = f;
    return (short)((v.u + 0x8000u) >> 16);
}

// ---------------- workspace layout (float offsets) ----------------
constexpr size_t OFF_WCOMB = 0;                           // 16*128
constexpr size_t OFF_BCOMB = 2048;                        // 128
constexpr size_t OFF_AEXP  = 2176;                        // 16
constexpr size_t OFF_WIGS  = 2192;                        // 65536 bf16 (32768 f)
constexpr size_t OFF_WBS   = 34960;                       // 4096 bf16 (2048 f)
constexpr size_t OFF_WCS   = 37008;                       // 2048 bf16 (1024 f)
constexpr size_t OFF_BM    = 38032;                       // ROWS*16
constexpr size_t OFF_CM    = OFF_BM + (size_t)ROWS * 16;  // ROWS*16 (end 26.4 MB)
// GAT scratch aliases the Bm region (dead after k2_scan):
constexpr size_t OFF_XT1   = OFF_BM;                      // 4*2048*64
constexpr size_t OFF_ES1   = OFF_XT1 + (size_t)HEADS * N_NODES * GHID;
constexpr size_t OFF_ED1   = OFF_ES1 + HEADS * N_NODES;
constexpr size_t OFF_H1    = OFF_ED1 + HEADS * N_NODES;   // 2048*256
constexpr size_t OFF_XT2   = OFF_H1 + (size_t)N_NODES * 256;
constexpr size_t OFF_ES2   = OFF_XT2 + (size_t)N_NODES * 64;
constexpr size_t OFF_ED2   = OFF_ES2 + N_NODES;

// ---------------- K0a: Wcomb = Wo[:16]@Wfc, bcomb = bo@Wfc+bfc, Aexp ----------------
// 17 blocks x 128 threads (was 1 block: single-CU serial dead time on the stream)
__global__ void k0_comb(const float* __restrict__ Wo, const float* __restrict__ bo,
                        const float* __restrict__ Wfc, const float* __restrict__ bfc,
                        const float* __restrict__ A_log, float* __restrict__ ws) {
    const int b = blockIdx.x, f2 = threadIdx.x;  // 128
    if (b < 16) {
        float a = 0.f;
        for (int f = 0; f < 128; f++) a += Wo[b * 128 + f] * Wfc[f * 128 + f2];
        ws[OFF_WCOMB + b * 128 + f2] = a;
    } else {
        float acc = bfc[f2];
        for (int f = 0; f < 128; f++) acc += bo[f] * Wfc[f * 128 + f2];
        ws[OFF_BCOMB + f2] = acc;
        if (f2 < 16) ws[OFF_AEXP + f2] = expf(0.01f * expf(A_log[f2]));
    }
}

// ---------------- K0b: swizzle Wi|Wg, Wb, Wc into bf16 B-fragment order ----------------
// B-frag layout (16x16x32): n = lane&15, k = (lane>>4)*8 + j, j=0..7
__global__ void k0_prep(const float* __restrict__ Wi, const float* __restrict__ Wg,
                        const float* __restrict__ Wb, const float* __restrict__ Wc,
                        float* __restrict__ ws) {
    int i = blockIdx.x * 256 + threadIdx.x;
    short* wigs = (short*)(ws + OFF_WIGS);
    short* wbs  = (short*)(ws + OFF_WBS);
    short* wcs  = (short*)(ws + OFF_WCS);
    if (i < 65536) {
        // nt = w*8 + t; t<4 -> I-tile cols 64w+16t.. ; t>=4 -> G-tile (same cols of Wg)
        int j = i & 7, lane = (i >> 3) & 63, ks = (i >> 9) & 3, nt = i >> 11;
        int w = nt >> 3, t = nt & 7;
        int col = w * 64 + (t & 3) * 16 + (lane & 15);
        int k   = ks * 32 + (lane >> 4) * 8 + j;
        float v = (t < 4) ? Wi[k * 256 + col] : Wg[k * 256 + col];
        wigs[i] = f2bf(v);
    } else if (i < 65536 + 4096) {
        int ii = i - 65536;
        int j = ii & 7, lane = (ii >> 3) & 63, ks = ii >> 9;       // ks 0..7
        int k = ks * 32 + (lane >> 4) * 8 + j, n = lane & 15;
        wbs[ii] = f2bf(Wb[k * 16 + n]);
    } else if (i < 65536 + 4096 + 2048) {
        int ii = i - 65536 - 4096;
        int j = ii & 7, lane = (ii >> 3) & 63, ks = ii >> 9;       // ks 0..3
        int k = ks * 32 + (lane >> 4) * 8 + j, n = lane & 15;
        wcs[ii] = f2bf(Wc[k * 16 + n]);
    }
}

// ---------------- K1: MFMA gated GEMM + gating + B/C GEMMs ----------------
// block = 64 rows, 4 waves; wave w owns I-cols & G-cols [64w, 64w+64)
__global__ __launch_bounds__(256) void k1_mfma(
    const float* __restrict__ temporal, const float* __restrict__ pos,
    const float* __restrict__ bi, const float* __restrict__ bg,
    const float* __restrict__ bb, const float* __restrict__ bc,
    const float* __restrict__ ws, float* __restrict__ Bm, float* __restrict__ Cm) {
    __shared__ short xbf[64][136];   // +8 pad: 2-way bank alias only (free)
    __shared__ short gbf[64][264];   // +8 pad
    const int tid = threadIdx.x, wave = tid >> 6, lane = tid & 63;
    const int m = lane & 15, quad = lane >> 4;
    const int r0 = blockIdx.x * 64;

    // stage x = temporal + pos -> bf16 LDS
#pragma unroll
    for (int i = 0; i < 8; i++) {
        int f4  = i * 256 + tid;          // 2048 float4s = 64 rows x 32
        int row = f4 >> 5;
        int c4  = (f4 & 31) * 4;
        int r = r0 + row, l = r % L_SEQ;
        float4 tv = *(const float4*)(temporal + (size_t)r * 128 + c4);
        float4 pv = *(const float4*)(pos + l * 128 + c4);
        short4 sv;
        sv.x = f2bf(tv.x + pv.x); sv.y = f2bf(tv.y + pv.y);
        sv.z = f2bf(tv.z + pv.z); sv.w = f2bf(tv.w + pv.w);
        *(short4*)&xbf[row][c4] = sv;
    }
    __syncthreads();

    // main gated GEMM: per wave 4 M-tiles x (4 I-tiles + 4 G-tiles), K=128
    const short* Wigs = (const short*)(ws + OFF_WIGS);
    floatx4 acc[4][8] = {};
#pragma unroll
    for (int ks = 0; ks < 4; ks++) {
        bf16x8 bfr[8];
#pragma unroll
        for (int nt = 0; nt < 8; nt++)
            bfr[nt] = *(const bf16x8*)(Wigs + (size_t)(((wave * 8 + nt) * 4 + ks) * 64 + lane) * 8);
        bf16x8 afr[4];
#pragma unroll
        for (int mt = 0; mt < 4; mt++)
            afr[mt] = *(const bf16x8*)&xbf[mt * 16 + m][ks * 32 + quad * 8];
#pragma unroll
        for (int mt = 0; mt < 4; mt++)
#pragma unroll
            for (int nt = 0; nt < 8; nt++)
                acc[mt][nt] = __builtin_amdgcn_mfma_f32_16x16x32_bf16(
                    afr[mt], bfr[nt], acc[mt][nt], 0, 0, 0);
    }

    // gating: gated = (I+bi)*sigmoid(G+bg), fast path:
    // sigmoid(x) = rcp(1 + exp2(-x*log2e)); C/D layout col=lane&15, row=quad*4+r
    const float NL2E = -1.44269504f;
#pragma unroll
    for (int tp = 0; tp < 4; tp++) {
        int col = wave * 64 + tp * 16 + m;
        float biv = bi[col];
        float bgs = bg[col] * NL2E;
#pragma unroll
        for (int mt = 0; mt < 4; mt++) {
#pragma unroll
            for (int r = 0; r < 4; r++) {
                float li = acc[mt][tp][r] + biv;
                float ex = __builtin_amdgcn_exp2f(fmaf(acc[mt][tp + 4][r], NL2E, bgs));
                float g  = li * __builtin_amdgcn_rcpf(1.f + ex);
                gbf[mt * 16 + quad * 4 + r][col] = f2bf(g);
            }
        }
    }
    __syncthreads();

    // B = gated@Wb + bb (K=256) ; C = x@Wc + bc (K=128); wave w -> M-tile w
    const short* Wbs = (const short*)(ws + OFF_WBS);
    const short* Wcs = (const short*)(ws + OFF_WCS);
    floatx4 accB = {}, accC = {};
#pragma unroll
    for (int ks = 0; ks < 8; ks++) {
        bf16x8 a = *(const bf16x8*)&gbf[wave * 16 + m][ks * 32 + quad * 8];
        bf16x8 b = *(const bf16x8*)(Wbs + (size_t)(ks * 64 + lane) * 8);
        accB = __builtin_amdgcn_mfma_f32_16x16x32_bf16(a, b, accB, 0, 0, 0);
    }
#pragma unroll
    for (int ks = 0; ks < 4; ks++) {
        bf16x8 a = *(const bf16x8*)&xbf[wave * 16 + m][ks * 32 + quad * 8];
        bf16x8 b = *(const bf16x8*)(Wcs + (size_t)(ks * 64 + lane) * 8);
        accC = __builtin_amdgcn_mfma_f32_16x16x32_bf16(a, b, accC, 0, 0, 0);
    }
    float bbv = bb[m], bcv = bc[m];
#pragma unroll
    for (int r = 0; r < 4; r++) {
        int row = r0 + wave * 16 + quad * 4 + r;
        Bm[(size_t)row * 16 + m] = accB[r] + bbv;
        Cm[(size_t)row * 16 + m] = accC[r] + bcv;
    }
}

// ---------------- K2: scan over L + fused y@Wcomb+bcomb epilogue ----------------
// B/C staged cooperatively into LDS (kills the uniform scalar-load chain)
__global__ __launch_bounds__(128) void k2_scan(const float* __restrict__ ws,
                                               float* __restrict__ out) {
    __shared__ float sb[1600], sc[1600];   // 100 x 16 each
    const int n = blockIdx.x, f = threadIdx.x;
    const float4* Bm4 = (const float4*)(ws + OFF_BM + (size_t)n * 1600);
    const float4* Cm4 = (const float4*)(ws + OFF_CM + (size_t)n * 1600);
#pragma unroll
    for (int i = 0; i < 4; i++) {
        int idx = i * 128 + f;
        if (idx < 400) {
            ((float4*)sb)[idx] = Bm4[idx];
            ((float4*)sc)[idx] = Cm4[idx];
        }
    }
    float w[16], A[16], h[16];
#pragma unroll
    for (int s = 0; s < 16; s++) {
        w[s] = ws[OFF_WCOMB + s * 128 + f];
        A[s] = ws[OFF_AEXP + s];
        h[s] = 0.f;
    }
    const float bcb = ws[OFF_BCOMB + f];
    __syncthreads();
    for (int l = 0; l < L_SEQ; l++) {
        float acc = bcb;
#pragma unroll
        for (int s = 0; s < 16; s++) {
            h[s] = A[s] * h[s] + sb[l * 16 + s];
            acc += h[s] * sc[l * 16 + s] * w[s];
        }
        out[((size_t)n * L_SEQ + l) * 128 + f] = acc;
    }
}

// ---------------- K4: xt1 = x@W1 per head, + es1/ed1 reductions ----------------
__global__ __launch_bounds__(64) void k4_xt1(const float* __restrict__ gx,
                                             const float* __restrict__ W1,
                                             const float* __restrict__ a1,
                                             float* __restrict__ ws) {
    const int b = blockIdx.x;     // 0..8191
    const int h = b >> 11;
    const int n = b & 2047;
    const int o = threadIdx.x;    // 64
    float acc = 0.f;
    for (int f = 0; f < 128; f++)
        acc += gx[n * 128 + f] * W1[(h * 128 + f) * 64 + o];
    ws[OFF_XT1 + ((size_t)h * 2048 + n) * 64 + o] = acc;
    float es = acc * a1[h * 128 + o];
    float ed = acc * a1[h * 128 + 64 + o];
#pragma unroll
    for (int off = 32; off > 0; off >>= 1) {
        es += __shfl_down(es, off);
        ed += __shfl_down(ed, off);
    }
    if (o == 0) { ws[OFF_ES1 + h * 2048 + n] = es; ws[OFF_ED1 + h * 2048 + n] = ed; }
}

// ---------------- K5: layer-1 attention (sparse) + relu -> h1 ----------------
__global__ __launch_bounds__(256) void k5_att1(const float* __restrict__ adj,
                                               const float* __restrict__ ws,
                                               float* __restrict__ h1out) {
    __shared__ int list[2048];
    __shared__ int cnt;
    const int n = blockIdx.x, tid = threadIdx.x;
    if (tid == 0) cnt = 0;
    __syncthreads();
    for (int j = tid; j < 2048; j += 256)
        if (adj[(size_t)n * 2048 + j] > 0.f) list[atomicAdd(&cnt, 1)] = j;
    __syncthreads();
    const int h = tid >> 6, o = tid & 63;
    const float  es = ws[OFF_ES1 + h * 2048 + n];
    const float* ed = ws + OFF_ED1 + h * 2048;
    const float* xt = ws + OFF_XT1 + (size_t)h * 2048 * 64;
    float num = 0.f, den = 0.f;
    const int mm = cnt;
    for (int ii = 0; ii < mm; ii++) {
        int j = list[ii];
        float e = es + ed[j];
        e = (e > 0.f) ? e : 0.2f * e;
        float wgt = expf(e);
        den += wgt;
        num += wgt * xt[(size_t)j * 64 + o];
    }
    float v = num / den;
    h1out[(size_t)n * 256 + h * 64 + o] = v > 0.f ? v : 0.f;
}

// ---------------- K6: xt2 = h1@W2 + es2/ed2 ----------------
__global__ __launch_bounds__(64) void k6_xt2(const float* __restrict__ W2,
                                             const float* __restrict__ a2,
                                             float* __restrict__ ws) {
    const int n = blockIdx.x, o = threadIdx.x;
    const float* h1 = ws + OFF_H1 + (size_t)n * 256;
    float acc = 0.f;
    for (int f = 0; f < 256; f++) acc += h1[f] * W2[f * 64 + o];
    ws[OFF_XT2 + (size_t)n * 64 + o] = acc;
    float es = acc * a2[o];
    float ed = acc * a2[64 + o];
#pragma unroll
    for (int off = 32; off > 0; off >>= 1) {
        es += __shfl_down(es, off);
        ed += __shfl_down(ed, off);
    }
    if (o == 0) { ws[OFF_ES2 + n] = es; ws[OFF_ED2 + n] = ed; }
}

// ---------------- K7: layer-2 attention (sparse) -> gat out ----------------
__global__ __launch_bounds__(64) void k7_att2(const float* __restrict__ adj,
                                              const float* __restrict__ ws,
                                              float* __restrict__ gout) {
    __shared__ int list[2048];
    __shared__ int cnt;
    const int n = blockIdx.x, o = threadIdx.x;
    if (o == 0) cnt = 0;
    __syncthreads();
    for (int j = o; j < 2048; j += 64)
        if (adj[(size_t)n * 2048 + j] > 0.f) list[atomicAdd(&cnt, 1)] = j;
    __syncthreads();
    const float es = ws[OFF_ES2 + n];
    float num = 0.f, den = 0.f;
    const int mm = cnt;
    for (int ii = 0; ii < mm; ii++) {
        int j = list[ii];
        float e = es + ws[OFF_ED2 + j];
        e = (e > 0.f) ? e : 0.2f * e;
        float wgt = expf(e);
        den += wgt;
        num += wgt * ws[OFF_XT2 + (size_t)j * 64 + o];
    }
    gout[(size_t)n * 64 + o] = num / den;
}

extern "C" void kernel_launch(void* const* d_in, const int* in_sizes, int n_in,
                              void* d_out, int out_size, void* d_ws, size_t ws_size,
                              hipStream_t stream) {
    const float* temporal = (const float*)d_in[0];
    const float* graph_x  = (const float*)d_in[1];
    const float* adj      = (const float*)d_in[2];
    const float* pos      = (const float*)d_in[3];
    const float* Wi  = (const float*)d_in[4];
    const float* bi  = (const float*)d_in[5];
    const float* Wg  = (const float*)d_in[6];
    const float* bg  = (const float*)d_in[7];
    const float* A_log = (const float*)d_in[8];
    const float* Wb  = (const float*)d_in[9];
    const float* bb  = (const float*)d_in[10];
    const float* Wc  = (const float*)d_in[11];
    const float* bc  = (const float*)d_in[12];
    const float* Wo  = (const float*)d_in[13];
    const float* bo  = (const float*)d_in[14];
    const float* Wfc = (const float*)d_in[15];
    const float* bfc = (const float*)d_in[16];
    const float* W1  = (const float*)d_in[17];
    const float* a1  = (const float*)d_in[18];
    const float* W2  = (const float*)d_in[19];
    const float* a2  = (const float*)d_in[20];

    float* ws = (float*)d_ws;
    float* out_mamba = (float*)d_out;
    float* out_gat   = out_mamba + (size_t)ROWS * 128;

    k0_comb<<<17, 128, 0, stream>>>(Wo, bo, Wfc, bfc, A_log, ws);
    k0_prep<<<280, 256, 0, stream>>>(Wi, Wg, Wb, Wc, ws);
    k1_mfma<<<ROWS / 64, 256, 0, stream>>>(temporal, pos, bi, bg, bb, bc, ws,
                                           ws + OFF_BM, ws + OFF_CM);
    k2_scan<<<N_NODES, 128, 0, stream>>>(ws, out_mamba);
    k4_xt1<<<HEADS * N_NODES, 64, 0, stream>>>(graph_x, W1, a1, ws);
    k5_att1<<<N_NODES, 256, 0, stream>>>(adj, ws, ws + OFF_H1);
    k6_xt2<<<N_NODES, 64, 0, stream>>>(W2, a2, ws);
    k7_att2<<<N_NODES, 64, 0, stream>>>(adj, ws, out_gat);
}